// Round 5
// baseline (100.307 us; speedup 1.0000x reference)
//
#include <hip/hip_runtime.h>
#include <hip/hip_bf16.h>
#include <stdint.h>

#define M_DIM 2048
#define K_DIM 4096
#define N_DIM 4096

typedef __attribute__((ext_vector_type(8))) short short8;
typedef __attribute__((ext_vector_type(4))) float f32x4;

#define MFMA __builtin_amdgcn_mfma_f32_16x16x32_bf16

// RNE float -> bf16, packed pair
__device__ __forceinline__ uint32_t bf16pk(float a, float b) {
  uint32_t ua = __float_as_uint(a);
  ua = (ua + 0x7FFFu + ((ua >> 16) & 1u)) >> 16;
  uint32_t ub = __float_as_uint(b);
  ub = (ub + 0x7FFFu + ((ub >> 16) & 1u)) >> 16;
  return ua | (ub << 16);
}

__device__ __forceinline__ void glds16(const char* g, char* l) {
  __builtin_amdgcn_global_load_lds((__attribute__((address_space(1))) void*)g,
                                   (__attribute__((address_space(3))) void*)l, 16, 0, 0);
}

// ---------------------------------------------------------------------------
// Image layout: BK=32 "steps" of 16KB, [k8-slot 0..3][row 0..255][16B].
// Byte-identical to R4's 32KB [slot 0..7][row][16B] tiles (verified R4).
//  xImg[mt 0..7][step 0..127]   (16.78 MB)
//  wImg[nt 0..15][step 0..127]  (33.55 MB)
// Staging = verbatim linear copy; frag reads 256B-contiguous per 16-lane
// group (R2/R4-measured 0 bank conflicts).
// ---------------------------------------------------------------------------

// Prepass 1: x fp32 -> xImg. grid 512 = mt*64 + kt (kt = 32KB pair of steps)
__global__ void __launch_bounds__(256) cvt_x_kernel(const float* __restrict__ x,
                                                    char* __restrict__ xImg) {
  const int mt = blockIdx.x >> 6, kt = blockIdx.x & 63;
  const int tid = threadIdx.x;
  const int k8 = tid & 7, rbase = tid >> 3;
  const float* xb = x + (size_t)mt * 256 * K_DIM + kt * 64 + k8 * 8;
  char* ob = xImg + (size_t)(mt * 64 + kt) * 32768 + k8 * 4096;
#pragma unroll
  for (int j = 0; j < 8; ++j) {
    int row = j * 32 + rbase;
    const float* src = xb + (size_t)row * K_DIM;
    float4 f0 = *(const float4*)src;
    float4 f1 = *(const float4*)(src + 4);
    uint4 pk;
    pk.x = bf16pk(f0.x, f0.y);
    pk.y = bf16pk(f0.z, f0.w);
    pk.z = bf16pk(f1.x, f1.y);
    pk.w = bf16pk(f1.z, f1.w);
    *(uint4*)(ob + row * 16) = pk;
  }
}

// Prepass 2: dequant int4 -> wImg. grid 1024 = nt*64 + kt
__global__ void __launch_bounds__(256) deq_w_kernel(const uint32_t* __restrict__ qweight,
                                                    const uint32_t* __restrict__ qzeros,
                                                    const float* __restrict__ scales,
                                                    char* __restrict__ wImg) {
  const int nt = blockIdx.x >> 6, kt = blockIdx.x & 63;
  const int t = threadIdx.x;
  const int n = nt * 256 + t;
  const int g = kt >> 1;
  uint32_t zq = qzeros[g * (N_DIM / 8) + (n >> 3)];
  const int z = (int)((zq >> ((n & 7) * 4)) & 15u) + 1;
  const float s = scales[g * N_DIM + n];
  char* ob = wImg + (size_t)(nt * 64 + kt) * 32768;
#pragma unroll
  for (int slot = 0; slot < 8; ++slot) {
    uint32_t q = qweight[(size_t)(kt * 8 + slot) * N_DIM + n];
    float f[8];
#pragma unroll
    for (int v = 0; v < 8; ++v) {
      int w = (int)((q >> (4 * v)) & 15u);
      f[v] = (float)(w - z) * s;               // exact int sub, cvt, mul
    }
    uint4 pk;
    pk.x = bf16pk(f[0], f[1]);
    pk.y = bf16pk(f[2], f[3]);
    pk.z = bf16pk(f[4], f[5]);
    pk.w = bf16pk(f[6], f[7]);
    *(uint4*)(ob + slot * 4096 + t * 16) = pk;
  }
}

// ---------------------------------------------------------------------------
// GEMM: BM=BN=256, 8 waves (2Mx4N), per-wave 128x64, K-split 2.
// Ring of 4 BK=32 slots (32KB each: A 16K + B 16K), depth-3 staging.
// Per step: 2 phases x 16 MFMA. Reads prefetched ONE PHASE EARLY with
// counted lgkmcnt; 6 reads issued per phase (balanced).
//
// Per-wave DS ledger (issue order, in-order retire):
//   ph_o(t-1): slot-t {a0..a3,b0,b1}            (6)
//   ph_e(t)  : slot-t {b2,b3,a4..a7}            (6)  + stage A(t+3)
//   ph_o(t)  : slot-(t+1) {a0..a3,b0,b1}        (6)  + stage B(t+3)
//   ph_e waits: lgkmcnt(6)->{a0-3,b0,b1} ready; 8 MFMA; lgkmcnt(4)->{b2,b3};
//   8 MFMA.  ph_o waits: lgkmcnt(6)->{a4-7}; 16 MFMA.
// Per-wave VM ledger (stages; 2 glds per A- or B-half):
//   prologue: A0 B0 A1 B1 A2 B2 (12), vmcnt(8) -> slot0 landed.
//   at ph_e(t) post-MFMA: outstanding {A(t+2),B(t+2),A(t+3)}=6 after
//   vmcnt(6) -> slot t+1 landed BEFORE the bar2 that precedes its reads.
//   tail: t=61 -> vmcnt(4); t=62 -> vmcnt(0); t=63 none.
// Slot overwrite safety: stage into slot (t-1)&3 issues >= 2 barrier-pairs
// after that slot's last reads, whose completion is forced by lgkmcnt
// before the preceding MFMA clusters.
// ---------------------------------------------------------------------------
__global__ void __launch_bounds__(512, 2) gemm_kernel(const char* __restrict__ xImg,
                                                      const char* __restrict__ wImg,
                                                      const float* __restrict__ bias,
                                                      float* __restrict__ out,
                                                      float* __restrict__ part1) {
  __shared__ uint4 ldsv[8192];                 // 131072 B = 4 slots x 32KB
  char* lds = (char*)ldsv;
  const int tid = threadIdx.x;
  const int lane = tid & 63, wid = tid >> 6;
  const int wr = wid >> 2, wc = wid & 3;       // 2M x 4N waves
  const int lr = lane & 15, lk = lane >> 4;

  // XCD-chunked mapping: xcd = bid&7 -> 2 B-panels (~4MB = L2-resident)
  const int bid = blockIdx.x;                  // 256 blocks
  const int i5 = bid >> 3;
  const int nb = (bid & 7) * 2 + (i5 & 1);
  const int mb = (i5 >> 1) & 7;
  const int ks = i5 >> 4;

  f32x4 acc[8][4];
#pragma unroll
  for (int i = 0; i < 8; ++i)
#pragma unroll
    for (int j = 0; j < 4; ++j) acc[i][j] = f32x4{0.f, 0.f, 0.f, 0.f};

  const char* aT = xImg + (size_t)(mb * 128 + ks * 64) * 16384;
  const char* bT = wImg + (size_t)(nb * 128 + ks * 64) * 16384;

  int aoff[8], boff[4];
#pragma unroll
  for (int i = 0; i < 8; ++i) aoff[i] = lk * 4096 + (wr * 128 + i * 16 + lr) * 16;
#pragma unroll
  for (int j = 0; j < 4; ++j) boff[j] = 16384 + lk * 4096 + (wc * 64 + j * 16 + lr) * 16;

#define STG(src, dstoff)                                                 \
  do {                                                                   \
    glds16((src) + tid * 16, lds + (dstoff) + tid * 16);                 \
    glds16((src) + 8192 + tid * 16, lds + (dstoff) + 8192 + tid * 16);   \
  } while (0)

  // prologue: stage slots 0..2
  STG(aT, 0);                STG(bT, 16384);
  STG(aT + 16384, 32768);    STG(bT + 16384, 32768 + 16384);
  STG(aT + 32768, 65536);    STG(bT + 32768, 65536 + 16384);
  asm volatile("s_waitcnt vmcnt(8)" ::: "memory");
  __builtin_amdgcn_sched_barrier(0);
  __builtin_amdgcn_s_barrier();

  // prologue reads: slot 0 {a0-3, b0, b1}
  short8 a0 = *(const short8*)(lds + aoff[0]);
  short8 a1 = *(const short8*)(lds + aoff[1]);
  short8 a2 = *(const short8*)(lds + aoff[2]);
  short8 a3 = *(const short8*)(lds + aoff[3]);
  short8 b0 = *(const short8*)(lds + boff[0]);
  short8 b1 = *(const short8*)(lds + boff[1]);

#pragma unroll 4
  for (int t = 0; t < 64; ++t) {
    const char* buf  = lds + (t & 3) * 32768;
    const char* bufn = lds + ((t + 1) & 3) * 32768;
    const int nso = ((t + 3) & 3) * 32768;
    const char* aN = aT + (size_t)(t + 3) * 16384;
    const char* bN = bT + (size_t)(t + 3) * 16384;

    // ===== phase E region-A: this step's late operands + next phase's A =====
    short8 b2 = *(const short8*)(buf + boff[2]);
    short8 b3 = *(const short8*)(buf + boff[3]);
    short8 a4 = *(const short8*)(buf + aoff[4]);
    short8 a5 = *(const short8*)(buf + aoff[5]);
    short8 a6 = *(const short8*)(buf + aoff[6]);
    short8 a7 = *(const short8*)(buf + aoff[7]);
    if (t <= 60) STG(aN, nso);
    __builtin_amdgcn_sched_barrier(0);
    __builtin_amdgcn_s_barrier();
    asm volatile("s_waitcnt lgkmcnt(6)" ::: "memory");
    __builtin_amdgcn_sched_barrier(0);
    __builtin_amdgcn_s_setprio(1);
    acc[0][0] = MFMA(a0, b0, acc[0][0], 0, 0, 0);
    acc[1][0] = MFMA(a1, b0, acc[1][0], 0, 0, 0);
    acc[2][0] = MFMA(a2, b0, acc[2][0], 0, 0, 0);
    acc[3][0] = MFMA(a3, b0, acc[3][0], 0, 0, 0);
    acc[0][1] = MFMA(a0, b1, acc[0][1], 0, 0, 0);
    acc[1][1] = MFMA(a1, b1, acc[1][1], 0, 0, 0);
    acc[2][1] = MFMA(a2, b1, acc[2][1], 0, 0, 0);
    acc[3][1] = MFMA(a3, b1, acc[3][1], 0, 0, 0);
    asm volatile("s_waitcnt lgkmcnt(4)" ::: "memory");
    __builtin_amdgcn_sched_barrier(0);
    acc[0][2] = MFMA(a0, b2, acc[0][2], 0, 0, 0);
    acc[1][2] = MFMA(a1, b2, acc[1][2], 0, 0, 0);
    acc[2][2] = MFMA(a2, b2, acc[2][2], 0, 0, 0);
    acc[3][2] = MFMA(a3, b2, acc[3][2], 0, 0, 0);
    acc[0][3] = MFMA(a0, b3, acc[0][3], 0, 0, 0);
    acc[1][3] = MFMA(a1, b3, acc[1][3], 0, 0, 0);
    acc[2][3] = MFMA(a2, b3, acc[2][3], 0, 0, 0);
    acc[3][3] = MFMA(a3, b3, acc[3][3], 0, 0, 0);
    __builtin_amdgcn_s_setprio(0);
    if (t <= 60)      asm volatile("s_waitcnt vmcnt(6)" ::: "memory");
    else if (t == 61) asm volatile("s_waitcnt vmcnt(4)" ::: "memory");
    else if (t == 62) asm volatile("s_waitcnt vmcnt(0)" ::: "memory");
    __builtin_amdgcn_sched_barrier(0);
    __builtin_amdgcn_s_barrier();
    __builtin_amdgcn_sched_barrier(0);

    // ===== phase O region-A: next step's early operands =====
    short8 na0 = *(const short8*)(bufn + aoff[0]);
    short8 na1 = *(const short8*)(bufn + aoff[1]);
    short8 na2 = *(const short8*)(bufn + aoff[2]);
    short8 na3 = *(const short8*)(bufn + aoff[3]);
    short8 nb0 = *(const short8*)(bufn + boff[0]);
    short8 nb1 = *(const short8*)(bufn + boff[1]);
    if (t <= 60) STG(bN, nso + 16384);
    __builtin_amdgcn_sched_barrier(0);
    __builtin_amdgcn_s_barrier();
    asm volatile("s_waitcnt lgkmcnt(6)" ::: "memory");
    __builtin_amdgcn_sched_barrier(0);
    __builtin_amdgcn_s_setprio(1);
    acc[4][0] = MFMA(a4, b0, acc[4][0], 0, 0, 0);
    acc[5][0] = MFMA(a5, b0, acc[5][0], 0, 0, 0);
    acc[6][0] = MFMA(a6, b0, acc[6][0], 0, 0, 0);
    acc[7][0] = MFMA(a7, b0, acc[7][0], 0, 0, 0);
    acc[4][1] = MFMA(a4, b1, acc[4][1], 0, 0, 0);
    acc[5][1] = MFMA(a5, b1, acc[5][1], 0, 0, 0);
    acc[6][1] = MFMA(a6, b1, acc[6][1], 0, 0, 0);
    acc[7][1] = MFMA(a7, b1, acc[7][1], 0, 0, 0);
    acc[4][2] = MFMA(a4, b2, acc[4][2], 0, 0, 0);
    acc[5][2] = MFMA(a5, b2, acc[5][2], 0, 0, 0);
    acc[6][2] = MFMA(a6, b2, acc[6][2], 0, 0, 0);
    acc[7][2] = MFMA(a7, b2, acc[7][2], 0, 0, 0);
    acc[4][3] = MFMA(a4, b3, acc[4][3], 0, 0, 0);
    acc[5][3] = MFMA(a5, b3, acc[5][3], 0, 0, 0);
    acc[6][3] = MFMA(a6, b3, acc[6][3], 0, 0, 0);
    acc[7][3] = MFMA(a7, b3, acc[7][3], 0, 0, 0);
    __builtin_amdgcn_s_setprio(0);
    __builtin_amdgcn_sched_barrier(0);
    __builtin_amdgcn_s_barrier();
    __builtin_amdgcn_sched_barrier(0);

    a0 = na0; a1 = na1; a2 = na2; a3 = na3; b0 = nb0; b1 = nb1;
  }
#undef STG

  // epilogue: C/D map col=lane&15, row=(lane>>4)*4+reg (verified R0-R4)
  const int colB = nb * 256 + wc * 64 + lr;
  const int rowB = mb * 256 + wr * 128 + lk * 4;
  if (part1 != nullptr) {
    float* dst = ks ? part1 : out;
#pragma unroll
    for (int j = 0; j < 4; ++j) {
      int col = colB + j * 16;
      float bj = (ks == 0) ? bias[col] : 0.f;
#pragma unroll
      for (int i = 0; i < 8; ++i) {
        int row = rowB + i * 16;
#pragma unroll
        for (int r = 0; r < 4; ++r)
          dst[(size_t)(row + r) * N_DIM + col] = acc[i][j][r] + bj;
      }
    }
  } else {
#pragma unroll
    for (int j = 0; j < 4; ++j) {
      int col = colB + j * 16;
      float bj = (ks == 0) ? bias[col] : 0.f;
#pragma unroll
      for (int i = 0; i < 8; ++i) {
        int row = rowB + i * 16;
#pragma unroll
        for (int r = 0; r < 4; ++r)
          atomicAdd(&out[(size_t)(row + r) * N_DIM + col], acc[i][j][r] + bj);
      }
    }
  }
}

// out += part1
__global__ void __launch_bounds__(256) reduce_kernel(float* __restrict__ out,
                                                     const float* __restrict__ part1) {
  int i = blockIdx.x * 256 + threadIdx.x;
  float4 o = ((const float4*)out)[i];
  float4 p = ((const float4*)part1)[i];
  o.x += p.x; o.y += p.y; o.z += p.z; o.w += p.w;
  ((float4*)out)[i] = o;
}

// ---------------------------------------------------------------------------
// Fallback (workspace too small)
// ---------------------------------------------------------------------------
__global__ void fallback_kernel(const float* __restrict__ x, const uint32_t* __restrict__ qweight,
                                const uint32_t* __restrict__ qzeros, const float* __restrict__ scales,
                                const float* __restrict__ bias, float* __restrict__ out) {
  __shared__ float xs[16][17];
  __shared__ float ws[16][17];
  int tx = threadIdx.x, ty = threadIdx.y;
  int col = blockIdx.x * 16 + tx;
  int row = blockIdx.y * 16 + ty;
  float acc = 0.f;
  for (int k0 = 0; k0 < K_DIM; k0 += 16) {
    xs[ty][tx] = x[(size_t)row * K_DIM + k0 + tx];
    int k = k0 + ty;
    int g = k >> 7;
    uint32_t q = qweight[(size_t)(k >> 3) * N_DIM + col];
    int w = (int)((q >> ((k & 7) * 4)) & 15u);
    uint32_t zq = qzeros[g * (N_DIM / 8) + (col >> 3)];
    int z = (int)((zq >> ((col & 7) * 4)) & 15u) + 1;
    ws[ty][tx] = (float)(w - z) * scales[g * N_DIM + col];
    __syncthreads();
#pragma unroll
    for (int kk = 0; kk < 16; ++kk) acc += xs[ty][kk] * ws[kk][tx];
    __syncthreads();
  }
  out[(size_t)row * N_DIM + col] = acc + bias[col];
}

extern "C" void kernel_launch(void* const* d_in, const int* in_sizes, int n_in,
                              void* d_out, int out_size, void* d_ws, size_t ws_size,
                              hipStream_t stream) {
  const float* x = (const float*)d_in[0];
  const uint32_t* qweight = (const uint32_t*)d_in[1];
  const uint32_t* qzeros = (const uint32_t*)d_in[2];
  const float* scales = (const float*)d_in[3];
  // d_in[4] = g_idx (== arange(K)//128, folded into index math)
  const float* bias = (const float*)d_in[5];
  float* out = (float*)d_out;

  const size_t X_IMG = (size_t)8 * 64 * 32768;    // 16.78 MB
  const size_t W_IMG = (size_t)16 * 64 * 32768;   // 33.55 MB
  const size_t PART = (size_t)M_DIM * N_DIM * 4;  // 33.55 MB

  if (ws_size >= X_IMG + W_IMG + PART) {
    char* xImg = (char*)d_ws;
    char* wImg = (char*)d_ws + X_IMG;
    float* part1 = (float*)((char*)d_ws + X_IMG + W_IMG);
    cvt_x_kernel<<<512, 256, 0, stream>>>(x, xImg);
    deq_w_kernel<<<1024, 256, 0, stream>>>(qweight, qzeros, scales, wImg);
    gemm_kernel<<<256, 512, 0, stream>>>((const char*)xImg, (const char*)wImg, bias, out, part1);
    reduce_kernel<<<8192, 256, 0, stream>>>(out, part1);
  } else if (ws_size >= X_IMG + W_IMG) {
    char* xImg = (char*)d_ws;
    char* wImg = (char*)d_ws + X_IMG;
    hipMemsetAsync(out, 0, (size_t)M_DIM * N_DIM * sizeof(float), stream);
    cvt_x_kernel<<<512, 256, 0, stream>>>(x, xImg);
    deq_w_kernel<<<1024, 256, 0, stream>>>(qweight, qzeros, scales, wImg);
    gemm_kernel<<<256, 512, 0, stream>>>((const char*)xImg, (const char*)wImg, bias, out, nullptr);
  } else {
    fallback_kernel<<<dim3(N_DIM / 16, M_DIM / 16), dim3(16, 16), 0, stream>>>(
        x, qweight, qzeros, scales, bias, out);
  }
}